// Round 10
// baseline (30220.486 us; speedup 1.0000x reference)
//
#include <hip/hip_runtime.h>

// ---- problem constants ----
#define NT 365
#define NB 512          // ngrid == hidden
#define NX4 16

typedef __attribute__((ext_vector_type(8))) short bf16x8;
typedef __attribute__((ext_vector_type(4))) float f32x4;
typedef __attribute__((ext_vector_type(4))) unsigned int u32x4;
typedef unsigned short u16;
typedef unsigned int u32;

// ---- workspace layout (bytes); R9 layout preserved, new bufs appended ----
static constexpr size_t WB_OFF  = 0;                                   // 4 x [2048][512] bf16
static constexpr size_t B0_OFF  = WB_OFF + 4ull * 2048 * 512 * 2;      // 2048 f32
static constexpr size_t B1_OFF  = B0_OFF + 2048 * 4;
static constexpr size_t X0_OFF  = B1_OFF + 2048 * 4;                   // [512][512] bf16
static constexpr size_t HT_OFF  = X0_OFF + 512 * 512 * 2;
static constexpr size_t HT0_OFF = HT_OFF + 512 * 512 * 2;
static constexpr size_t G0_OFF  = HT0_OFF + 512 * 512 * 2;             // 4 x [512][512] bf16
static constexpr size_t G1_OFF  = G0_OFF + 4ull * 512 * 512 * 2;       // 4 x [512][512] bf16
static constexpr size_t CT_OFF  = G1_OFF + 4ull * 512 * 512 * 2;       // [512][512] f32
static constexpr size_t VSP_OFF = CT_OFF + 512ull * 512 * 4;           // [256 wg][8 slot][368] f32
static constexpr size_t NRM_OFF = VSP_OFF + 256ull * 8 * 368 * 4;      // [368] f32
static constexpr size_t G0X_OFF = (NRM_OFF + 368 * 4 + 255) & ~255ull; // [4][512][512] f32
static constexpr size_t G1X_OFF = G0X_OFF + 4ull * 512 * 512 * 4;      // [4][512][512] f32
static constexpr size_t WS_NEED = G1X_OFF + 4ull * 512 * 512 * 4;

__device__ __forceinline__ u16 f2bf(float f) {
  u32 u = __builtin_bit_cast(u32, f);
  return (u16)((u + 0x7fffu + ((u >> 16) & 1u)) >> 16);
}
__device__ __forceinline__ float bf2f(u16 h) {
  u32 u = ((u32)h) << 16;
  return __builtin_bit_cast(float, u);
}
__device__ __forceinline__ float sigf(float x) { return 1.0f / (1.0f + __expf(-x)); }
__device__ __forceinline__ float tanha(float x) { return 1.0f - 2.0f / (__expf(2.0f * x) + 1.0f); }

// ================= prep =================
__global__ __launch_bounds__(1024) void prep_k(
    const float* __restrict__ xg, const float* __restrict__ Win, const float* __restrict__ bin,
    const float* __restrict__ Wih0, const float* __restrict__ bih0,
    const float* __restrict__ Whh0, const float* __restrict__ bhh0,
    const float* __restrict__ Wih1, const float* __restrict__ bih1,
    const float* __restrict__ Whh1, const float* __restrict__ bhh1,
    const float* __restrict__ bout, float* __restrict__ out, char* __restrict__ ws) {
  u16* wb = (u16*)(ws + WB_OFF);
  float* b0 = (float*)(ws + B0_OFF);
  float* b1 = (float*)(ws + B1_OFF);
  u16* x0b = (u16*)(ws + X0_OFF);
  u16* htb = (u16*)(ws + HT_OFF);
  float* ctb = (float*)(ws + CT_OFF);
  const int gtid = blockIdx.x * 1024 + threadIdx.x;   // 0..262143

  const float* srcs[4] = {Wih0, Whh0, Wih1, Whh1};
  #pragma unroll
  for (int mm = 0; mm < 4; ++mm) {
    const float4* s4 = (const float4*)srcs[mm];
    float4 v = s4[gtid];
    ushort4 o;
    o.x = f2bf(v.x); o.y = f2bf(v.y); o.z = f2bf(v.z); o.w = f2bf(v.w);
    ((ushort4*)(wb + (size_t)mm * 2048 * 512))[gtid] = o;
  }
  if (gtid < 2048) { b0[gtid] = bih0[gtid] + bhh0[gtid]; b1[gtid] = bih1[gtid] + bhh1[gtid]; }
  if (gtid < 131072) ((u32*)htb)[gtid] = 0u;
  ctb[gtid] = 0.0f;
  { // x0 for t=0
    int b = gtid >> 9, h = gtid & 511;
    const float* xr = xg + (size_t)b * NX4;
    const float* wr = Win + (size_t)h * NX4;
    float a = bin[h];
    #pragma unroll
    for (int j = 0; j < 16; ++j) a += wr[j] * xr[j];
    x0b[gtid] = f2bf(fmaxf(a, 0.0f));
  }
  { // out = bias
    float bo = bout[0];
    for (int j = gtid; j < NT * NB; j += 262144) out[j] = bo;
  }
}

// ================= xproj tile: gx[M] = x0 @ W^T + b (K=512) =================
// M=0: Wih0 (slot0) + b0 -> g0x ; M=1: Wih1 (slot2) + b1 -> g1x
__device__ __forceinline__ void xproj_tile(char* __restrict__ ws, int M, int j, int tid) {
  u16* wb = (u16*)(ws + WB_OFF);
  const float* bias = (const float*)(ws + (M ? B1_OFF : B0_OFF));
  const u16* x0b = (const u16*)(ws + X0_OFF);
  float* gx = (float*)(ws + (M ? G1X_OFF : G0X_OFF));
  const u16* W = wb + (size_t)(M ? 2 : 0) * 2048 * 512;
  const int r = j >> 4, c = j & 15;
  const int rbase = r * 32, cbase = c * 32;
  const int w = tid >> 6, lane = tid & 63, l15 = lane & 15, kg = lane >> 4;
  const int g = w >> 2, m = (w >> 1) & 1, n = w & 1;
  const int wrow = g * 512 + cbase + n * 16 + l15;
  const u16* Wr = W + (size_t)wrow * 512;
  const u16* Ar = x0b + (size_t)(rbase + m * 16 + l15) * 512;
  f32x4 acc = {0.f, 0.f, 0.f, 0.f};
  const float bb = bias[wrow];
  #pragma unroll
  for (int ks = 0; ks < 16; ++ks) {
    int kk = ks * 32 + kg * 8;
    bf16x8 a = *(const bf16x8*)(Ar + kk);
    bf16x8 q = *(const bf16x8*)(Wr + kk);
    acc = __builtin_amdgcn_mfma_f32_16x16x32_bf16(a, q, acc, 0, 0, 0);
  }
  #pragma unroll
  for (int q = 0; q < 4; ++q) {
    int row = rbase + m * 16 + kg * 4 + q;
    gx[(size_t)g * 262144 + (size_t)row * 512 + cbase + n * 16 + l15] = acc[q] + bb;
  }
}

__global__ __launch_bounds__(1024) void xproj0_k(char* __restrict__ ws) {
  xproj_tile(ws, blockIdx.x >> 8, blockIdx.x & 255, threadIdx.x);
}

// ================= P1h: g0 = g0x + ht @ Whh0^T -> act -> ct, ht0, g0b =================
__global__ __launch_bounds__(1024) void p1h_k(char* __restrict__ ws) {
  __shared__ u16 gFu[5120];
  u16* wb = (u16*)(ws + WB_OFF);
  const u16* htb = (const u16*)(ws + HT_OFF);
  u16* ht0b = (u16*)(ws + HT0_OFF);
  u16* g0b = (u16*)(ws + G0_OFF);
  float* ctb = (float*)(ws + CT_OFF);
  const float* g0x = (const float*)(ws + G0X_OFF);

  const int tid = threadIdx.x, gid = blockIdx.x;
  const int r = gid >> 4, c = gid & 15;   // c%8 = XCD -> weight slice L2-resident
  const int rbase = r * 32, cbase = c * 32;
  const int w = tid >> 6, lane = tid & 63, l15 = lane & 15, kg = lane >> 4;
  const int g = w >> 2, m = (w >> 1) & 1, n = w & 1;
  const int urow = tid >> 5, ucol = tid & 31;
  const int ub = rbase + urow, uh = cbase + ucol;

  f32x4 acc;
  #pragma unroll
  for (int q = 0; q < 4; ++q)
    acc[q] = g0x[(size_t)g * 262144 + (size_t)(rbase + m * 16 + kg * 4 + q) * 512 + cbase + n * 16 + l15];
  {
    const u16* Wr = wb + 1ull * 2048 * 512 + (size_t)(g * 512 + cbase + n * 16 + l15) * 512; // Whh0
    const u16* Ar = htb + (size_t)(rbase + m * 16 + l15) * 512;
    #pragma unroll
    for (int ks = 0; ks < 16; ++ks) {
      int kk = ks * 32 + kg * 8;
      bf16x8 a = *(const bf16x8*)(Ar + kk);
      bf16x8 q = *(const bf16x8*)(Wr + kk);
      acc = __builtin_amdgcn_mfma_f32_16x16x32_bf16(a, q, acc, 0, 0, 0);
    }
  }
  #pragma unroll
  for (int q = 0; q < 4; ++q) {
    float v = acc[q];
    float a = (g == 2) ? tanha(v) : sigf(v);
    gFu[g * 1280 + (m * 16 + kg * 4 + q) * 40 + n * 16 + l15] = f2bf(a);
  }
  __syncthreads();
  {
    u16 gi = gFu[0 * 1280 + urow * 40 + ucol];
    u16 gf = gFu[1 * 1280 + urow * 40 + ucol];
    u16 gc = gFu[2 * 1280 + urow * 40 + ucol];
    u16 go = gFu[3 * 1280 + urow * 40 + ucol];
    float i0 = bf2f(gi), f0 = bf2f(gf), c0 = bf2f(gc), o0 = bf2f(go);
    size_t eo = (size_t)ub * 512 + uh;
    float ctv = ctb[eo];
    ctv = f0 * ctv + i0 * c0;
    float h0v = o0 * tanha(ctv);
    ctb[eo] = ctv;
    ht0b[eo] = f2bf(h0v);
    g0b[0 * 262144 + eo] = gi;
    g0b[1 * 262144 + eo] = gf;
    g0b[2 * 262144 + eo] = gc;
    g0b[3 * 262144 + eo] = go;
  }
}

// ================= P2h: g1 = g1x + ht0 @ Whh1^T ; x0(t+1) =================
__global__ __launch_bounds__(1024) void p2h_k(
    char* __restrict__ ws, const float* __restrict__ xg, const float* __restrict__ Win,
    const float* __restrict__ bin, int t) {
  u16* wb = (u16*)(ws + WB_OFF);
  u16* x0b = (u16*)(ws + X0_OFF);
  const u16* ht0b = (const u16*)(ws + HT0_OFF);
  u16* g1b = (u16*)(ws + G1_OFF);
  const float* g1x = (const float*)(ws + G1X_OFF);

  const int tid = threadIdx.x, gid = blockIdx.x;
  const int r = gid >> 4, c = gid & 15;
  const int rbase = r * 32, cbase = c * 32;
  const int w = tid >> 6, lane = tid & 63, l15 = lane & 15, kg = lane >> 4;
  const int g = w >> 2, m = (w >> 1) & 1, n = w & 1;
  const int urow = tid >> 5, ucol = tid & 31;
  const int ub = rbase + urow, uh = cbase + ucol;

  f32x4 acc;
  #pragma unroll
  for (int q = 0; q < 4; ++q)
    acc[q] = g1x[(size_t)g * 262144 + (size_t)(rbase + m * 16 + kg * 4 + q) * 512 + cbase + n * 16 + l15];
  {
    const u16* Wr = wb + 3ull * 2048 * 512 + (size_t)(g * 512 + cbase + n * 16 + l15) * 512; // Whh1
    const u16* Ar = ht0b + (size_t)(rbase + m * 16 + l15) * 512;
    #pragma unroll
    for (int ks = 0; ks < 16; ++ks) {
      int kk = ks * 32 + kg * 8;
      bf16x8 a = *(const bf16x8*)(Ar + kk);
      bf16x8 q = *(const bf16x8*)(Wr + kk);
      acc = __builtin_amdgcn_mfma_f32_16x16x32_bf16(a, q, acc, 0, 0, 0);
    }
  }
  #pragma unroll
  for (int q = 0; q < 4; ++q) {
    int b_ = rbase + m * 16 + kg * 4 + q;
    g1b[(size_t)g * 262144 + (size_t)b_ * 512 + cbase + n * 16 + l15] = f2bf(acc[q]);
  }
  if (t + 1 < NT) {   // next step's input projection
    const float* xr = xg + ((size_t)(t + 1) * NB + ub) * NX4;
    const float* wr = Win + (size_t)uh * NX4;
    float a = bin[uh];
    #pragma unroll
    for (int j = 0; j < 16; ++j) a += wr[j] * xr[j];
    x0b[(size_t)ub * 512 + uh] = f2bf(fmaxf(a, 0.0f));
  }
}

// ================= P3 + xproj(t+1): grid 768 =================
__global__ __launch_bounds__(1024) void p3x_k(
    char* __restrict__ ws, const float* __restrict__ Wout, float* __restrict__ out, int t) {
  const int tid = threadIdx.x, gid = blockIdx.x;
  if (gid >= 256) {
    if (t + 1 < NT) { int jj = gid - 256; xproj_tile(ws, jj >> 8, jj & 255, tid); }
    return;
  }
  __shared__ u16 gFu[5120];
  __shared__ float sv[32];
  u16* htb = (u16*)(ws + HT_OFF);
  const u16* g0b = (const u16*)(ws + G0_OFF);
  const u16* g1b = (const u16*)(ws + G1_OFF);
  float* ctb = (float*)(ws + CT_OFF);
  float* vspb = (float*)(ws + VSP_OFF);

  const int r = gid >> 4, c = gid & 15;
  const int rbase = r * 32, cbase = c * 32;
  const int w = tid >> 6, lane = tid & 63, l15 = lane & 15, kg = lane >> 4;
  const int g = w >> 2, m = (w >> 1) & 1, n = w & 1;
  const int urow = tid >> 5, ucol = tid & 31;
  const int ub = rbase + urow, uh = cbase + ucol;

  {
    f32x4 acc = {0.f, 0.f, 0.f, 0.f};
    const u16* As = g0b + (size_t)g * 262144 + (size_t)(rbase + m * 16 + l15) * 512;
    const u16* Bs = g1b + (size_t)g * 262144 + (size_t)(cbase + n * 16 + l15) * 512;
    #pragma unroll
    for (int ks = 0; ks < 16; ++ks) {
      int kk = ks * 32 + kg * 8;
      bf16x8 a = *(const bf16x8*)(As + kk);
      bf16x8 q = *(const bf16x8*)(Bs + kk);
      acc = __builtin_amdgcn_mfma_f32_16x16x32_bf16(a, q, acc, 0, 0, 0);
    }
    float s1 = acc[0] + acc[1] + acc[2] + acc[3];
    float s2 = acc[0] * acc[0] + acc[1] * acc[1] + acc[2] * acc[2] + acc[3] * acc[3];
    #pragma unroll
    for (int off = 32; off > 0; off >>= 1) { s1 += __shfl_xor(s1, off); s2 += __shfl_xor(s2, off); }
    if (lane == 0) { sv[w * 2] = s1; sv[w * 2 + 1] = s2; }
    #pragma unroll
    for (int q = 0; q < 4; ++q)
      gFu[g * 1280 + (m * 16 + kg * 4 + q) * 40 + n * 16 + l15] = f2bf(acc[q]);
  }
  __syncthreads();
  {
    float i1 = sigf(bf2f(gFu[0 * 1280 + urow * 40 + ucol]));
    float f1 = sigf(bf2f(gFu[1 * 1280 + urow * 40 + ucol]));
    float c1 = tanha(bf2f(gFu[2 * 1280 + urow * 40 + ucol]));
    float o1 = sigf(bf2f(gFu[3 * 1280 + urow * 40 + ucol]));
    size_t eo = (size_t)ub * 512 + uh;
    float ctv = ctb[eo];
    ctv = f1 * ctv + i1 * c1;
    float hv = o1 * tanha(ctv);
    ctb[eo] = ctv;
    htb[eo] = f2bf(hv);
    float op = hv * Wout[uh];
    op += __shfl_down(op, 16, 32);
    op += __shfl_down(op, 8, 32);
    op += __shfl_down(op, 4, 32);
    op += __shfl_down(op, 2, 32);
    op += __shfl_down(op, 1, 32);
    if ((tid & 31) == 0) atomicAdd(out + (size_t)t * NB + ub, op);
    if (tid < 8) {
      int gg = tid >> 1, part = tid & 1;
      float val = sv[(gg * 4 + 0) * 2 + part] + sv[(gg * 4 + 1) * 2 + part] +
                  sv[(gg * 4 + 2) * 2 + part] + sv[(gg * 4 + 3) * 2 + part];
      vspb[((size_t)gid * 8 + tid) * 368 + t] = val;
    }
  }
}

// ================= fallback path (R9-proven kernels) =================
__global__ __launch_bounds__(1024) void p1_k(char* __restrict__ ws) {
  __shared__ __align__(16) char lraw[65536];
  u16* gFu = (u16*)lraw;
  u16* wb = (u16*)(ws + WB_OFF);
  float* b0 = (float*)(ws + B0_OFF);
  u16* x0b = (u16*)(ws + X0_OFF);
  u16* htb = (u16*)(ws + HT_OFF);
  u16* ht0b = (u16*)(ws + HT0_OFF);
  u16* g0b = (u16*)(ws + G0_OFF);
  float* ctb = (float*)(ws + CT_OFF);

  const int tid = threadIdx.x, gid = blockIdx.x;
  const int r = gid >> 4, c = gid & 15;
  const int rbase = r * 32, cbase = c * 32;
  const int w = tid >> 6, lane = tid & 63, l15 = lane & 15, kg = lane >> 4;
  const int g = w >> 2, m = (w >> 1) & 1, n = w & 1;
  const int urow = tid >> 5, ucol = tid & 31;
  const int ub = rbase + urow, uh = cbase + ucol;
  const int arow = m * 16 + l15, abase = arow << 11, axor = (arow & 7) << 4;
  const u16* Wl0 = wb + (size_t)(g * 512 + cbase + n * 16 + l15) * 512;
  const float bias0l = b0[g * 512 + cbase + n * 16 + l15];

  #pragma unroll
  for (int p = 0; p < 4; ++p) {
    int ch = p * 1024 + tid;
    int row = ch >> 7, cc = ch & 127;
    const u16* sp = (cc < 64) ? x0b + (size_t)(rbase + row) * 512 + cc * 8
                              : htb + (size_t)(rbase + row) * 512 + (cc - 64) * 8;
    u32x4 v = *(const u32x4*)sp;
    *(u32x4*)&lraw[(row << 11) | ((cc << 4) ^ ((row & 7) << 4))] = v;
  }
  __syncthreads();
  f32x4 acc = {0.f, 0.f, 0.f, 0.f};
  {
    const u16* W0 = Wl0;
    const u16* W1 = Wl0 + 2048ull * 512;
    #pragma unroll
    for (int ks = 0; ks < 16; ++ks) {
      int kk = ks * 32 + kg * 8;
      bf16x8 a = *(const bf16x8*)&lraw[abase | (((kk >> 3) << 4) ^ axor)];
      bf16x8 q = *(const bf16x8*)(W0 + kk);
      acc = __builtin_amdgcn_mfma_f32_16x16x32_bf16(a, q, acc, 0, 0, 0);
    }
    #pragma unroll
    for (int ks = 0; ks < 16; ++ks) {
      int kk = ks * 32 + kg * 8;
      bf16x8 a = *(const bf16x8*)&lraw[abase | (((64 + (kk >> 3)) << 4) ^ axor)];
      bf16x8 q = *(const bf16x8*)(W1 + kk);
      acc = __builtin_amdgcn_mfma_f32_16x16x32_bf16(a, q, acc, 0, 0, 0);
    }
  }
  __syncthreads();
  #pragma unroll
  for (int q = 0; q < 4; ++q) {
    float v = acc[q] + bias0l;
    float a = (g == 2) ? tanha(v) : sigf(v);
    gFu[g * 1280 + (m * 16 + kg * 4 + q) * 40 + n * 16 + l15] = f2bf(a);
  }
  __syncthreads();
  {
    u16 gi = gFu[0 * 1280 + urow * 40 + ucol];
    u16 gf = gFu[1 * 1280 + urow * 40 + ucol];
    u16 gc = gFu[2 * 1280 + urow * 40 + ucol];
    u16 go = gFu[3 * 1280 + urow * 40 + ucol];
    float i0 = bf2f(gi), f0 = bf2f(gf), c0 = bf2f(gc), o0 = bf2f(go);
    size_t eo = (size_t)ub * 512 + uh;
    float ctv = ctb[eo];
    ctv = f0 * ctv + i0 * c0;
    float h0v = o0 * tanha(ctv);
    ctb[eo] = ctv;
    ht0b[eo] = f2bf(h0v);
    g0b[0 * 262144 + eo] = gi;
    g0b[1 * 262144 + eo] = gf;
    g0b[2 * 262144 + eo] = gc;
    g0b[3 * 262144 + eo] = go;
  }
}

__global__ __launch_bounds__(1024) void p2_k(char* __restrict__ ws) {
  __shared__ __align__(16) char lraw[65536];
  u16* wb = (u16*)(ws + WB_OFF);
  float* b1 = (float*)(ws + B1_OFF);
  u16* x0b = (u16*)(ws + X0_OFF);
  u16* ht0b = (u16*)(ws + HT0_OFF);
  u16* g1b = (u16*)(ws + G1_OFF);

  const int tid = threadIdx.x, gid = blockIdx.x;
  const int r = gid >> 4, c = gid & 15;
  const int rbase = r * 32, cbase = c * 32;
  const int w = tid >> 6, lane = tid & 63, l15 = lane & 15, kg = lane >> 4;
  const int g = w >> 2, m = (w >> 1) & 1, n = w & 1;
  const int arow = m * 16 + l15, abase = arow << 11, axor = (arow & 7) << 4;
  const u16* Wl0 = wb + (size_t)(g * 512 + cbase + n * 16 + l15) * 512;
  const float bias1l = b1[g * 512 + cbase + n * 16 + l15];

  #pragma unroll
  for (int p = 0; p < 4; ++p) {
    int ch = p * 1024 + tid;
    int row = ch >> 7, cc = ch & 127;
    const u16* sp = (cc < 64) ? x0b + (size_t)(rbase + row) * 512 + cc * 8
                              : ht0b + (size_t)(rbase + row) * 512 + (cc - 64) * 8;
    u32x4 v = *(const u32x4*)sp;
    *(u32x4*)&lraw[(row << 11) | ((cc << 4) ^ ((row & 7) << 4))] = v;
  }
  __syncthreads();
  f32x4 acc = {0.f, 0.f, 0.f, 0.f};
  {
    const u16* W0 = Wl0 + 2ull * 2048 * 512;
    const u16* W1 = Wl0 + 3ull * 2048 * 512;
    #pragma unroll
    for (int ks = 0; ks < 16; ++ks) {
      int kk = ks * 32 + kg * 8;
      bf16x8 a = *(const bf16x8*)&lraw[abase | (((kk >> 3) << 4) ^ axor)];
      bf16x8 q = *(const bf16x8*)(W0 + kk);
      acc = __builtin_amdgcn_mfma_f32_16x16x32_bf16(a, q, acc, 0, 0, 0);
    }
    #pragma unroll
    for (int ks = 0; ks < 16; ++ks) {
      int kk = ks * 32 + kg * 8;
      bf16x8 a = *(const bf16x8*)&lraw[abase | (((64 + (kk >> 3)) << 4) ^ axor)];
      bf16x8 q = *(const bf16x8*)(W1 + kk);
      acc = __builtin_amdgcn_mfma_f32_16x16x32_bf16(a, q, acc, 0, 0, 0);
    }
  }
  #pragma unroll
  for (int q = 0; q < 4; ++q) {
    int b_ = rbase + m * 16 + kg * 4 + q;
    g1b[(size_t)g * 262144 + (size_t)b_ * 512 + cbase + n * 16 + l15] = f2bf(acc[q] + bias1l);
  }
}

__global__ __launch_bounds__(1024) void p3_k(
    char* __restrict__ ws, const float* __restrict__ xg, const float* __restrict__ Win,
    const float* __restrict__ bin, const float* __restrict__ Wout,
    float* __restrict__ out, int t) {
  __shared__ u16 gFu[5120];
  __shared__ float sv[32];
  u16* x0b = (u16*)(ws + X0_OFF);
  u16* htb = (u16*)(ws + HT_OFF);
  u16* g0b = (u16*)(ws + G0_OFF);
  u16* g1b = (u16*)(ws + G1_OFF);
  float* ctb = (float*)(ws + CT_OFF);
  float* vspb = (float*)(ws + VSP_OFF);

  const int tid = threadIdx.x, gid = blockIdx.x;
  const int r = gid >> 4, c = gid & 15;
  const int rbase = r * 32, cbase = c * 32;
  const int w = tid >> 6, lane = tid & 63, l15 = lane & 15, kg = lane >> 4;
  const int g = w >> 2, m = (w >> 1) & 1, n = w & 1;
  const int urow = tid >> 5, ucol = tid & 31;
  const int ub = rbase + urow, uh = cbase + ucol;

  {
    f32x4 acc = {0.f, 0.f, 0.f, 0.f};
    const u16* As = g0b + (size_t)g * 262144 + (size_t)(rbase + m * 16 + l15) * 512;
    const u16* Bs = g1b + (size_t)g * 262144 + (size_t)(cbase + n * 16 + l15) * 512;
    #pragma unroll
    for (int ks = 0; ks < 16; ++ks) {
      int kk = ks * 32 + kg * 8;
      bf16x8 a = *(const bf16x8*)(As + kk);
      bf16x8 q = *(const bf16x8*)(Bs + kk);
      acc = __builtin_amdgcn_mfma_f32_16x16x32_bf16(a, q, acc, 0, 0, 0);
    }
    float s1 = acc[0] + acc[1] + acc[2] + acc[3];
    float s2 = acc[0] * acc[0] + acc[1] * acc[1] + acc[2] * acc[2] + acc[3] * acc[3];
    #pragma unroll
    for (int off = 32; off > 0; off >>= 1) { s1 += __shfl_xor(s1, off); s2 += __shfl_xor(s2, off); }
    if (lane == 0) { sv[w * 2] = s1; sv[w * 2 + 1] = s2; }
    #pragma unroll
    for (int q = 0; q < 4; ++q)
      gFu[g * 1280 + (m * 16 + kg * 4 + q) * 40 + n * 16 + l15] = f2bf(acc[q]);
  }
  __syncthreads();
  {
    float i1 = sigf(bf2f(gFu[0 * 1280 + urow * 40 + ucol]));
    float f1 = sigf(bf2f(gFu[1 * 1280 + urow * 40 + ucol]));
    float c1 = tanha(bf2f(gFu[2 * 1280 + urow * 40 + ucol]));
    float o1 = sigf(bf2f(gFu[3 * 1280 + urow * 40 + ucol]));
    size_t eo = (size_t)ub * 512 + uh;
    float ctv = ctb[eo];
    ctv = f1 * ctv + i1 * c1;
    float hv = o1 * tanha(ctv);
    ctb[eo] = ctv;
    htb[eo] = f2bf(hv);
    float op = hv * Wout[uh];
    op += __shfl_down(op, 16, 32);
    op += __shfl_down(op, 8, 32);
    op += __shfl_down(op, 4, 32);
    op += __shfl_down(op, 2, 32);
    op += __shfl_down(op, 1, 32);
    if ((tid & 31) == 0) atomicAdd(out + (size_t)t * NB + ub, op);
    if (tid < 8) {
      int gg = tid >> 1, part = tid & 1;
      float val = sv[(gg * 4 + 0) * 2 + part] + sv[(gg * 4 + 1) * 2 + part] +
                  sv[(gg * 4 + 2) * 2 + part] + sv[(gg * 4 + 3) * 2 + part];
      vspb[((size_t)gid * 8 + tid) * 368 + t] = val;
    }
    if (t + 1 < NT) {
      const float* xr = xg + ((size_t)(t + 1) * NB + ub) * NX4;
      const float* wr = Win + (size_t)uh * NX4;
      float a = bin[uh];
      #pragma unroll
      for (int j = 0; j < 16; ++j) a += wr[j] * xr[j];
      x0b[eo] = f2bf(fmaxf(a, 0.0f));
    }
  }
}

// ================= variance / final =================
__global__ __launch_bounds__(256) void var_k(char* __restrict__ ws) {
  __shared__ float sred[8];
  float* vspb = (float*)(ws + VSP_OFF);
  float* normp = (float*)(ws + NRM_OFF);
  const int tt = blockIdx.x;
  const int tid = threadIdx.x;
  const int s = tid >> 5, jb = tid & 31;
  float v = 0.0f;
  for (int j = jb; j < 256; j += 32) v += vspb[((size_t)j * 8 + s) * 368 + tt];
  #pragma unroll
  for (int off = 16; off > 0; off >>= 1) v += __shfl_xor(v, off, 32);
  if (jb == 0) sred[s] = v;
  __syncthreads();
  if (tid == 0) {
    const float invN = 1.0f / 262144.0f;
    float var4 = 0.0f;
    #pragma unroll
    for (int gg = 0; gg < 4; ++gg) {
      float sum = sred[gg * 2 + 0];
      float sq  = sred[gg * 2 + 1];
      float mean = sum * invN;
      var4 += sq * invN - mean * mean;
    }
    normp[tt] = var4 * 0.25f;
  }
}

__global__ __launch_bounds__(512) void final_k(char* __restrict__ ws, float* __restrict__ out) {
  __shared__ float red[8];
  float* normp = (float*)(ws + NRM_OFF);
  const int tid = threadIdx.x;
  float s = (tid < NT) ? normp[tid] : 0.0f;
  #pragma unroll
  for (int off = 32; off > 0; off >>= 1) s += __shfl_xor(s, off);
  if ((tid & 63) == 0) red[tid >> 6] = s;
  __syncthreads();
  if (tid == 0) {
    float tot = 0.0f;
    #pragma unroll
    for (int j = 0; j < 8; ++j) tot += red[j];
    out[NT * NB] = tot / (float)NT;
  }
}

extern "C" void kernel_launch(void* const* d_in, const int* in_sizes, int n_in,
                              void* d_out, int out_size, void* d_ws, size_t ws_size,
                              hipStream_t stream) {
  const float* xg = (const float*)d_in[0];
  const float* Win = (const float*)d_in[1];
  const float* bin = (const float*)d_in[2];
  const float* Wih0 = (const float*)d_in[3];
  const float* bih0 = (const float*)d_in[4];
  const float* Whh0 = (const float*)d_in[5];
  const float* bhh0 = (const float*)d_in[6];
  const float* Wih1 = (const float*)d_in[7];
  const float* bih1 = (const float*)d_in[8];
  const float* Whh1 = (const float*)d_in[9];
  const float* bhh1 = (const float*)d_in[10];
  const float* Wout = (const float*)d_in[11];
  const float* bout = (const float*)d_in[12];
  float* out = (float*)d_out;
  char* ws = (char*)d_ws;

  hipLaunchKernelGGL(prep_k, dim3(256), dim3(1024), 0, stream,
                     xg, Win, bin, Wih0, bih0, Whh0, bhh0, Wih1, bih1, Whh1, bhh1,
                     bout, out, ws);
  if (ws_size >= WS_NEED) {
    hipLaunchKernelGGL(xproj0_k, dim3(512), dim3(1024), 0, stream, ws);
    for (int t = 0; t < NT; ++t) {
      hipLaunchKernelGGL(p1h_k, dim3(256), dim3(1024), 0, stream, ws);
      hipLaunchKernelGGL(p2h_k, dim3(256), dim3(1024), 0, stream, ws, xg, Win, bin, t);
      hipLaunchKernelGGL(p3x_k, dim3(768), dim3(1024), 0, stream, ws, Wout, out, t);
    }
  } else {
    for (int t = 0; t < NT; ++t) {
      hipLaunchKernelGGL(p1_k, dim3(256), dim3(1024), 0, stream, ws);
      hipLaunchKernelGGL(p2_k, dim3(256), dim3(1024), 0, stream, ws);
      hipLaunchKernelGGL(p3_k, dim3(256), dim3(1024), 0, stream, ws, xg, Win, bin, Wout, out, t);
    }
  }
  hipLaunchKernelGGL(var_k, dim3(365), dim3(256), 0, stream, ws);
  hipLaunchKernelGGL(final_k, dim3(1), dim3(512), 0, stream, ws, out);
}

// Round 12
// 30205.194 us; speedup vs baseline: 1.0005x; 1.0005x over previous
//
#include <hip/hip_runtime.h>

// ---- problem constants ----
#define NT 365
#define NB 512          // ngrid == hidden
#define NX4 16

typedef __attribute__((ext_vector_type(8))) short bf16x8;
typedef __attribute__((ext_vector_type(4))) float f32x4;
typedef unsigned short u16;
typedef unsigned int u32;

// ---- workspace layout (bytes); R9 layout ----
static constexpr size_t WB_OFF  = 0;                                   // 4 x [2048][512] bf16
static constexpr size_t B0_OFF  = WB_OFF + 4ull * 2048 * 512 * 2;      // 2048 f32
static constexpr size_t B1_OFF  = B0_OFF + 2048 * 4;
static constexpr size_t X0_OFF  = B1_OFF + 2048 * 4;                   // [512][512] bf16
static constexpr size_t HT_OFF  = X0_OFF + 512 * 512 * 2;
static constexpr size_t HT0_OFF = HT_OFF + 512 * 512 * 2;
static constexpr size_t G0_OFF  = HT0_OFF + 512 * 512 * 2;             // 4 x [512][512] bf16
static constexpr size_t G1_OFF  = G0_OFF + 4ull * 512 * 512 * 2;       // 4 x [512][512] bf16
static constexpr size_t CT_OFF  = G1_OFF + 4ull * 512 * 512 * 2;       // [512][512] f32
static constexpr size_t VSP_OFF = CT_OFF + 512ull * 512 * 4;           // [256 wg][8 slot][368] f32
static constexpr size_t NRM_OFF = VSP_OFF + 256ull * 8 * 368 * 4;      // [368] f32

__device__ __forceinline__ u16 f2bf(float f) {
  u32 u = __builtin_bit_cast(u32, f);
  return (u16)((u + 0x7fffu + ((u >> 16) & 1u)) >> 16);
}
__device__ __forceinline__ float bf2f(u16 h) {
  u32 u = ((u32)h) << 16;
  return __builtin_bit_cast(float, u);
}
__device__ __forceinline__ float sigf(float x) { return 1.0f / (1.0f + __expf(-x)); }
__device__ __forceinline__ float tanha(float x) { return 1.0f - 2.0f / (__expf(2.0f * x) + 1.0f); }

// ================= prep =================
__global__ __launch_bounds__(1024) void prep_k(
    const float* __restrict__ xg, const float* __restrict__ Win, const float* __restrict__ bin,
    const float* __restrict__ Wih0, const float* __restrict__ bih0,
    const float* __restrict__ Whh0, const float* __restrict__ bhh0,
    const float* __restrict__ Wih1, const float* __restrict__ bih1,
    const float* __restrict__ Whh1, const float* __restrict__ bhh1,
    const float* __restrict__ bout, float* __restrict__ out, char* __restrict__ ws) {
  u16* wb = (u16*)(ws + WB_OFF);
  float* b0 = (float*)(ws + B0_OFF);
  float* b1 = (float*)(ws + B1_OFF);
  u16* x0b = (u16*)(ws + X0_OFF);
  u16* htb = (u16*)(ws + HT_OFF);
  float* ctb = (float*)(ws + CT_OFF);
  const int gtid = blockIdx.x * 1024 + threadIdx.x;   // 0..262143

  const float* srcs[4] = {Wih0, Whh0, Wih1, Whh1};
  #pragma unroll
  for (int mm = 0; mm < 4; ++mm) {
    const float4* s4 = (const float4*)srcs[mm];
    float4 v = s4[gtid];
    ushort4 o;
    o.x = f2bf(v.x); o.y = f2bf(v.y); o.z = f2bf(v.z); o.w = f2bf(v.w);
    ((ushort4*)(wb + (size_t)mm * 2048 * 512))[gtid] = o;
  }
  if (gtid < 2048) { b0[gtid] = bih0[gtid] + bhh0[gtid]; b1[gtid] = bih1[gtid] + bhh1[gtid]; }
  if (gtid < 131072) ((u32*)htb)[gtid] = 0u;
  ctb[gtid] = 0.0f;
  { // x0 for t=0
    int b = gtid >> 9, h = gtid & 511;
    const float* xr = xg + (size_t)b * NX4;
    const float* wr = Win + (size_t)h * NX4;
    float a = bin[h];
    #pragma unroll
    for (int j = 0; j < 16; ++j) a += wr[j] * xr[j];
    x0b[gtid] = f2bf(fmaxf(a, 0.0f));
  }
  { // out = bias
    float bo = bout[0];
    for (int j = gtid; j < NT * NB; j += 262144) out[j] = bo;
  }
}

// ================= P1: layer-0 gates + cell update (direct-global A loads) =================
__global__ __launch_bounds__(1024) void p1_k(char* __restrict__ ws) {
  __shared__ u16 gFu[5120];
  u16* wb = (u16*)(ws + WB_OFF);
  float* b0 = (float*)(ws + B0_OFF);
  const u16* x0b = (const u16*)(ws + X0_OFF);
  const u16* htb = (const u16*)(ws + HT_OFF);
  u16* ht0b = (u16*)(ws + HT0_OFF);
  u16* g0b = (u16*)(ws + G0_OFF);
  float* ctb = (float*)(ws + CT_OFF);

  const int tid = threadIdx.x, gid = blockIdx.x;
  const int r = gid >> 4, c = gid & 15;   // c%8 = XCD -> weight slice L2-resident
  const int rbase = r * 32, cbase = c * 32;
  const int w = tid >> 6, lane = tid & 63, l15 = lane & 15, kg = lane >> 4;
  const int g = w >> 2, m = (w >> 1) & 1, n = w & 1;
  const int urow = tid >> 5, ucol = tid & 31;
  const int ub = rbase + urow, uh = cbase + ucol;
  const float bias0l = b0[g * 512 + cbase + n * 16 + l15];

  f32x4 acc = {0.f, 0.f, 0.f, 0.f};
  {
    const u16* Ax = x0b + (size_t)(rbase + m * 16 + l15) * 512;
    const u16* Ah = htb + (size_t)(rbase + m * 16 + l15) * 512;
    const u16* W0 = wb + (size_t)(g * 512 + cbase + n * 16 + l15) * 512;  // Wih0 row
    const u16* W1 = W0 + 2048ull * 512;                                    // Whh0 row
    #pragma unroll
    for (int ks = 0; ks < 16; ++ks) {
      int kk = ks * 32 + kg * 8;
      bf16x8 a = *(const bf16x8*)(Ax + kk);
      bf16x8 q = *(const bf16x8*)(W0 + kk);
      acc = __builtin_amdgcn_mfma_f32_16x16x32_bf16(a, q, acc, 0, 0, 0);
    }
    #pragma unroll
    for (int ks = 0; ks < 16; ++ks) {
      int kk = ks * 32 + kg * 8;
      bf16x8 a = *(const bf16x8*)(Ah + kk);
      bf16x8 q = *(const bf16x8*)(W1 + kk);
      acc = __builtin_amdgcn_mfma_f32_16x16x32_bf16(a, q, acc, 0, 0, 0);
    }
  }
  #pragma unroll
  for (int q = 0; q < 4; ++q) {
    float v = acc[q] + bias0l;
    float a = (g == 2) ? tanha(v) : sigf(v);
    gFu[g * 1280 + (m * 16 + kg * 4 + q) * 40 + n * 16 + l15] = f2bf(a);
  }
  __syncthreads();
  {
    u16 gi = gFu[0 * 1280 + urow * 40 + ucol];
    u16 gf = gFu[1 * 1280 + urow * 40 + ucol];
    u16 gc = gFu[2 * 1280 + urow * 40 + ucol];
    u16 go = gFu[3 * 1280 + urow * 40 + ucol];
    float i0 = bf2f(gi), f0 = bf2f(gf), c0 = bf2f(gc), o0 = bf2f(go);
    size_t eo = (size_t)ub * 512 + uh;
    float ctv = ctb[eo];
    ctv = f0 * ctv + i0 * c0;
    float h0v = o0 * tanha(ctv);
    ctb[eo] = ctv;
    ht0b[eo] = f2bf(h0v);
    g0b[0 * 262144 + eo] = gi;
    g0b[1 * 262144 + eo] = gf;
    g0b[2 * 262144 + eo] = gc;
    g0b[3 * 262144 + eo] = go;
  }
}

// ================= P2: layer-1 raw gates (direct-global A loads) =================
__global__ __launch_bounds__(1024) void p2_k(char* __restrict__ ws) {
  u16* wb = (u16*)(ws + WB_OFF);
  float* b1 = (float*)(ws + B1_OFF);
  const u16* x0b = (const u16*)(ws + X0_OFF);
  const u16* ht0b = (const u16*)(ws + HT0_OFF);
  u16* g1b = (u16*)(ws + G1_OFF);

  const int tid = threadIdx.x, gid = blockIdx.x;
  const int r = gid >> 4, c = gid & 15;
  const int rbase = r * 32, cbase = c * 32;
  const int w = tid >> 6, lane = tid & 63, l15 = lane & 15, kg = lane >> 4;
  const int g = w >> 2, m = (w >> 1) & 1, n = w & 1;
  const float bias1l = b1[g * 512 + cbase + n * 16 + l15];

  f32x4 acc = {0.f, 0.f, 0.f, 0.f};
  {
    const u16* Ax = x0b + (size_t)(rbase + m * 16 + l15) * 512;
    const u16* Ah = ht0b + (size_t)(rbase + m * 16 + l15) * 512;
    const u16* W0 = wb + 2ull * 2048 * 512 + (size_t)(g * 512 + cbase + n * 16 + l15) * 512; // Wih1
    const u16* W1 = W0 + 2048ull * 512;                                                       // Whh1
    #pragma unroll
    for (int ks = 0; ks < 16; ++ks) {
      int kk = ks * 32 + kg * 8;
      bf16x8 a = *(const bf16x8*)(Ax + kk);
      bf16x8 q = *(const bf16x8*)(W0 + kk);
      acc = __builtin_amdgcn_mfma_f32_16x16x32_bf16(a, q, acc, 0, 0, 0);
    }
    #pragma unroll
    for (int ks = 0; ks < 16; ++ks) {
      int kk = ks * 32 + kg * 8;
      bf16x8 a = *(const bf16x8*)(Ah + kk);
      bf16x8 q = *(const bf16x8*)(W1 + kk);
      acc = __builtin_amdgcn_mfma_f32_16x16x32_bf16(a, q, acc, 0, 0, 0);
    }
  }
  #pragma unroll
  for (int q = 0; q < 4; ++q) {
    int b_ = rbase + m * 16 + kg * 4 + q;
    g1b[(size_t)g * 262144 + (size_t)b_ * 512 + cbase + n * 16 + l15] = f2bf(acc[q] + bias1l);
  }
}

// ================= P3: [B,B] score matmuls + layer-1 update + outputs + x0(t+1) =================
// x0(t+1) write lives HERE: p3_k never reads x0b, so no intra-kernel race (R11 lesson).
__global__ __launch_bounds__(1024) void p3_k(
    char* __restrict__ ws, const float* __restrict__ xg, const float* __restrict__ Win,
    const float* __restrict__ bin, const float* __restrict__ Wout,
    float* __restrict__ out, int t) {
  __shared__ u16 gFu[5120];
  __shared__ float sv[32];
  u16* x0b = (u16*)(ws + X0_OFF);
  u16* htb = (u16*)(ws + HT_OFF);
  const u16* g0b = (const u16*)(ws + G0_OFF);
  const u16* g1b = (const u16*)(ws + G1_OFF);
  float* ctb = (float*)(ws + CT_OFF);
  float* vspb = (float*)(ws + VSP_OFF);

  const int tid = threadIdx.x, gid = blockIdx.x;
  const int r = gid >> 4, c = gid & 15;
  const int rbase = r * 32, cbase = c * 32;
  const int w = tid >> 6, lane = tid & 63, l15 = lane & 15, kg = lane >> 4;
  const int g = w >> 2, m = (w >> 1) & 1, n = w & 1;
  const int urow = tid >> 5, ucol = tid & 31;
  const int ub = rbase + urow, uh = cbase + ucol;

  {
    f32x4 acc = {0.f, 0.f, 0.f, 0.f};
    const u16* As = g0b + (size_t)g * 262144 + (size_t)(rbase + m * 16 + l15) * 512;
    const u16* Bs = g1b + (size_t)g * 262144 + (size_t)(cbase + n * 16 + l15) * 512;
    #pragma unroll
    for (int ks = 0; ks < 16; ++ks) {
      int kk = ks * 32 + kg * 8;
      bf16x8 a = *(const bf16x8*)(As + kk);
      bf16x8 q = *(const bf16x8*)(Bs + kk);
      acc = __builtin_amdgcn_mfma_f32_16x16x32_bf16(a, q, acc, 0, 0, 0);
    }
    float s1 = acc[0] + acc[1] + acc[2] + acc[3];
    float s2 = acc[0] * acc[0] + acc[1] * acc[1] + acc[2] * acc[2] + acc[3] * acc[3];
    #pragma unroll
    for (int off = 32; off > 0; off >>= 1) { s1 += __shfl_xor(s1, off); s2 += __shfl_xor(s2, off); }
    if (lane == 0) { sv[w * 2] = s1; sv[w * 2 + 1] = s2; }
    #pragma unroll
    for (int q = 0; q < 4; ++q)
      gFu[g * 1280 + (m * 16 + kg * 4 + q) * 40 + n * 16 + l15] = f2bf(acc[q]);
  }
  __syncthreads();
  {
    float i1 = sigf(bf2f(gFu[0 * 1280 + urow * 40 + ucol]));
    float f1 = sigf(bf2f(gFu[1 * 1280 + urow * 40 + ucol]));
    float c1 = tanha(bf2f(gFu[2 * 1280 + urow * 40 + ucol]));
    float o1 = sigf(bf2f(gFu[3 * 1280 + urow * 40 + ucol]));
    size_t eo = (size_t)ub * 512 + uh;
    float ctv = ctb[eo];
    ctv = f1 * ctv + i1 * c1;
    float hv = o1 * tanha(ctv);
    ctb[eo] = ctv;
    htb[eo] = f2bf(hv);
    float op = hv * Wout[uh];
    op += __shfl_down(op, 16, 32);
    op += __shfl_down(op, 8, 32);
    op += __shfl_down(op, 4, 32);
    op += __shfl_down(op, 2, 32);
    op += __shfl_down(op, 1, 32);
    if ((tid & 31) == 0) atomicAdd(out + (size_t)t * NB + ub, op);
    if (tid < 8) {   // per-wg variance slot
      int gg = tid >> 1, part = tid & 1;
      float val = sv[(gg * 4 + 0) * 2 + part] + sv[(gg * 4 + 1) * 2 + part] +
                  sv[(gg * 4 + 2) * 2 + part] + sv[(gg * 4 + 3) * 2 + part];
      vspb[((size_t)gid * 8 + tid) * 368 + t] = val;
    }
    if (t + 1 < NT) {   // next step's input projection
      const float* xr = xg + ((size_t)(t + 1) * NB + ub) * NX4;
      const float* wr = Win + (size_t)uh * NX4;
      float a = bin[uh];
      #pragma unroll
      for (int j = 0; j < 16; ++j) a += wr[j] * xr[j];
      x0b[eo] = f2bf(fmaxf(a, 0.0f));
    }
  }
}

// ================= variance / final =================
__global__ __launch_bounds__(256) void var_k(char* __restrict__ ws) {
  __shared__ float sred[8];
  float* vspb = (float*)(ws + VSP_OFF);
  float* normp = (float*)(ws + NRM_OFF);
  const int tt = blockIdx.x;
  const int tid = threadIdx.x;
  const int s = tid >> 5, jb = tid & 31;
  float v = 0.0f;
  for (int j = jb; j < 256; j += 32) v += vspb[((size_t)j * 8 + s) * 368 + tt];
  #pragma unroll
  for (int off = 16; off > 0; off >>= 1) v += __shfl_xor(v, off, 32);
  if (jb == 0) sred[s] = v;
  __syncthreads();
  if (tid == 0) {
    const float invN = 1.0f / 262144.0f;
    float var4 = 0.0f;
    #pragma unroll
    for (int gg = 0; gg < 4; ++gg) {
      float sum = sred[gg * 2 + 0];
      float sq  = sred[gg * 2 + 1];
      float mean = sum * invN;
      var4 += sq * invN - mean * mean;
    }
    normp[tt] = var4 * 0.25f;
  }
}

__global__ __launch_bounds__(512) void final_k(char* __restrict__ ws, float* __restrict__ out) {
  __shared__ float red[8];
  float* normp = (float*)(ws + NRM_OFF);
  const int tid = threadIdx.x;
  float s = (tid < NT) ? normp[tid] : 0.0f;
  #pragma unroll
  for (int off = 32; off > 0; off >>= 1) s += __shfl_xor(s, off);
  if ((tid & 63) == 0) red[tid >> 6] = s;
  __syncthreads();
  if (tid == 0) {
    float tot = 0.0f;
    #pragma unroll
    for (int j = 0; j < 8; ++j) tot += red[j];
    out[NT * NB] = tot / (float)NT;
  }
}

extern "C" void kernel_launch(void* const* d_in, const int* in_sizes, int n_in,
                              void* d_out, int out_size, void* d_ws, size_t ws_size,
                              hipStream_t stream) {
  const float* xg = (const float*)d_in[0];
  const float* Win = (const float*)d_in[1];
  const float* bin = (const float*)d_in[2];
  const float* Wih0 = (const float*)d_in[3];
  const float* bih0 = (const float*)d_in[4];
  const float* Whh0 = (const float*)d_in[5];
  const float* bhh0 = (const float*)d_in[6];
  const float* Wih1 = (const float*)d_in[7];
  const float* bih1 = (const float*)d_in[8];
  const float* Whh1 = (const float*)d_in[9];
  const float* bhh1 = (const float*)d_in[10];
  const float* Wout = (const float*)d_in[11];
  const float* bout = (const float*)d_in[12];
  float* out = (float*)d_out;
  char* ws = (char*)d_ws;

  hipLaunchKernelGGL(prep_k, dim3(256), dim3(1024), 0, stream,
                     xg, Win, bin, Wih0, bih0, Whh0, bhh0, Wih1, bih1, Whh1, bhh1,
                     bout, out, ws);
  for (int t = 0; t < NT; ++t) {
    hipLaunchKernelGGL(p1_k, dim3(256), dim3(1024), 0, stream, ws);
    hipLaunchKernelGGL(p2_k, dim3(256), dim3(1024), 0, stream, ws);
    hipLaunchKernelGGL(p3_k, dim3(256), dim3(1024), 0, stream, ws, xg, Win, bin, Wout, out, t);
  }
  hipLaunchKernelGGL(var_k, dim3(365), dim3(256), 0, stream, ws);
  hipLaunchKernelGGL(final_k, dim3(1), dim3(512), 0, stream, ws, out);
}

// Round 13
// 22316.444 us; speedup vs baseline: 1.3542x; 1.3535x over previous
//
#include <hip/hip_runtime.h>

// ---- problem constants ----
#define NT 365
#define NB 512          // ngrid == hidden
#define NX4 16

typedef __attribute__((ext_vector_type(8))) short bf16x8;
typedef __attribute__((ext_vector_type(4))) float f32x4;
typedef __attribute__((ext_vector_type(4))) unsigned int u32x4;
typedef unsigned short u16;
typedef unsigned int u32;

// ---- workspace layout (bytes) ----
static constexpr size_t WB_OFF  = 0;                                   // 4 x [2048][512] bf16
static constexpr size_t B0_OFF  = WB_OFF + 4ull * 2048 * 512 * 2;      // 2048 f32
static constexpr size_t B1_OFF  = B0_OFF + 2048 * 4;
static constexpr size_t X0_OFF  = B1_OFF + 2048 * 4;                   // [512][512] bf16
static constexpr size_t HT_OFF  = X0_OFF + 512 * 512 * 2;
static constexpr size_t HT0_OFF = HT_OFF + 512 * 512 * 2;
static constexpr size_t G0_OFF  = HT0_OFF + 512 * 512 * 2;             // 4 x [512][512] bf16
static constexpr size_t G1_OFF  = G0_OFF + 4ull * 512 * 512 * 2;       // 4 x [512][512] bf16
static constexpr size_t CT_OFF  = G1_OFF + 4ull * 512 * 512 * 2;       // [512][512] f32
static constexpr size_t VSP_OFF = CT_OFF + 512ull * 512 * 4;           // [512 wg][8 slot][368] f32
static constexpr size_t NRM_OFF = VSP_OFF + 512ull * 8 * 368 * 4;      // [368] f32

__device__ __forceinline__ u16 f2bf(float f) {
  u32 u = __builtin_bit_cast(u32, f);
  return (u16)((u + 0x7fffu + ((u >> 16) & 1u)) >> 16);
}
__device__ __forceinline__ float bf2f(u16 h) {
  u32 u = ((u32)h) << 16;
  return __builtin_bit_cast(float, u);
}
__device__ __forceinline__ float sigf(float x) { return 1.0f / (1.0f + __expf(-x)); }
__device__ __forceinline__ float tanha(float x) { return 1.0f - 2.0f / (__expf(2.0f * x) + 1.0f); }

// ================= prep =================
__global__ __launch_bounds__(1024) void prep_k(
    const float* __restrict__ xg, const float* __restrict__ Win, const float* __restrict__ bin,
    const float* __restrict__ Wih0, const float* __restrict__ bih0,
    const float* __restrict__ Whh0, const float* __restrict__ bhh0,
    const float* __restrict__ Wih1, const float* __restrict__ bih1,
    const float* __restrict__ Whh1, const float* __restrict__ bhh1,
    const float* __restrict__ bout, float* __restrict__ out, char* __restrict__ ws) {
  u16* wb = (u16*)(ws + WB_OFF);
  float* b0 = (float*)(ws + B0_OFF);
  float* b1 = (float*)(ws + B1_OFF);
  u16* x0b = (u16*)(ws + X0_OFF);
  u16* htb = (u16*)(ws + HT_OFF);
  float* ctb = (float*)(ws + CT_OFF);
  const int gtid = blockIdx.x * 1024 + threadIdx.x;   // 0..262143

  const float* srcs[4] = {Wih0, Whh0, Wih1, Whh1};
  #pragma unroll
  for (int mm = 0; mm < 4; ++mm) {
    const float4* s4 = (const float4*)srcs[mm];
    float4 v = s4[gtid];
    ushort4 o;
    o.x = f2bf(v.x); o.y = f2bf(v.y); o.z = f2bf(v.z); o.w = f2bf(v.w);
    ((ushort4*)(wb + (size_t)mm * 2048 * 512))[gtid] = o;
  }
  if (gtid < 2048) { b0[gtid] = bih0[gtid] + bhh0[gtid]; b1[gtid] = bih1[gtid] + bhh1[gtid]; }
  if (gtid < 131072) ((u32*)htb)[gtid] = 0u;
  ctb[gtid] = 0.0f;
  { // x0 for t=0
    int b = gtid >> 9, h = gtid & 511;
    const float* xr = xg + (size_t)b * NX4;
    const float* wr = Win + (size_t)h * NX4;
    float a = bin[h];
    #pragma unroll
    for (int j = 0; j < 16; ++j) a += wr[j] * xr[j];
    x0b[gtid] = f2bf(fmaxf(a, 0.0f));
  }
  { // out = bias
    float bo = bout[0];
    for (int j = gtid; j < NT * NB; j += 262144) out[j] = bo;
  }
}

// ================= P1: layer-0 gates + cell update (512 wgs x 512 thr, 2/CU) =================
__global__ __launch_bounds__(512, 4) void p1_k(char* __restrict__ ws) {
  __shared__ __align__(16) char lraw[65536];
  u16* gFu = (u16*)lraw;               // [4][32][17] bf16 aliased over staging
  u16* wb = (u16*)(ws + WB_OFF);
  float* b0 = (float*)(ws + B0_OFF);
  const u16* x0b = (const u16*)(ws + X0_OFF);
  const u16* htb = (const u16*)(ws + HT_OFF);
  u16* ht0b = (u16*)(ws + HT0_OFF);
  u16* g0b = (u16*)(ws + G0_OFF);
  float* ctb = (float*)(ws + CT_OFF);

  const int tid = threadIdx.x, gid = blockIdx.x;
  const int r = gid >> 5, c16 = gid & 31;   // gid%8 = c16%8 -> weight slice L2-resident per XCD
  const int rbase = r * 32, cbase = c16 * 16;
  const int w2 = tid >> 6, lane = tid & 63, l15 = lane & 15, kg = lane >> 4;
  const int g = w2 >> 1, m = w2 & 1;        // 8 waves: gate g, row-half m
  const int urow = tid >> 4, ucol = tid & 15;
  const int ub = rbase + urow, uh = cbase + ucol;
  const float bias0l = b0[g * 512 + cbase + l15];

  #pragma unroll
  for (int p = 0; p < 8; ++p) {   // stage [x0 | ht] rows rbase..+32 (64KB, swizzled)
    int ch = p * 512 + tid;
    int row = ch >> 7, cc = ch & 127;
    const u16* sp = (cc < 64) ? x0b + (size_t)(rbase + row) * 512 + cc * 8
                              : htb + (size_t)(rbase + row) * 512 + (cc - 64) * 8;
    u32x4 v = *(const u32x4*)sp;
    *(u32x4*)&lraw[(row << 11) | ((cc << 4) ^ ((row & 7) << 4))] = v;
  }
  __syncthreads();
  f32x4 acc = {0.f, 0.f, 0.f, 0.f};
  {
    const int abase = (m * 16 + l15) << 11;
    const int axor = ((m * 16 + l15) & 7) << 4;
    const u16* W0 = wb + (size_t)(g * 512 + cbase + l15) * 512;  // Wih0 row
    const u16* W1 = W0 + 2048ull * 512;                           // Whh0 row
    #pragma unroll
    for (int ks = 0; ks < 16; ++ks) {
      int kk = ks * 32 + kg * 8;
      bf16x8 a = *(const bf16x8*)&lraw[abase | (((kk >> 3) << 4) ^ axor)];
      bf16x8 q = *(const bf16x8*)(W0 + kk);
      acc = __builtin_amdgcn_mfma_f32_16x16x32_bf16(a, q, acc, 0, 0, 0);
    }
    #pragma unroll
    for (int ks = 0; ks < 16; ++ks) {
      int kk = ks * 32 + kg * 8;
      bf16x8 a = *(const bf16x8*)&lraw[abase | (((64 + (kk >> 3)) << 4) ^ axor)];
      bf16x8 q = *(const bf16x8*)(W1 + kk);
      acc = __builtin_amdgcn_mfma_f32_16x16x32_bf16(a, q, acc, 0, 0, 0);
    }
  }
  __syncthreads();  // staging dead; reuse LDS as gFu
  #pragma unroll
  for (int q = 0; q < 4; ++q) {
    float v = acc[q] + bias0l;
    float a = (g == 2) ? tanha(v) : sigf(v);
    gFu[g * 544 + (m * 16 + kg * 4 + q) * 17 + l15] = f2bf(a);
  }
  __syncthreads();
  {
    u16 gi = gFu[0 * 544 + urow * 17 + ucol];
    u16 gf = gFu[1 * 544 + urow * 17 + ucol];
    u16 gc = gFu[2 * 544 + urow * 17 + ucol];
    u16 go = gFu[3 * 544 + urow * 17 + ucol];
    float i0 = bf2f(gi), f0 = bf2f(gf), c0 = bf2f(gc), o0 = bf2f(go);
    size_t eo = (size_t)ub * 512 + uh;
    float ctv = ctb[eo];
    ctv = f0 * ctv + i0 * c0;
    float h0v = o0 * tanha(ctv);
    ctb[eo] = ctv;
    ht0b[eo] = f2bf(h0v);
    g0b[0 * 262144 + eo] = gi;
    g0b[1 * 262144 + eo] = gf;
    g0b[2 * 262144 + eo] = gc;
    g0b[3 * 262144 + eo] = go;
  }
}

// ================= P2: layer-1 raw gates (512 wgs x 512 thr) =================
__global__ __launch_bounds__(512, 4) void p2_k(char* __restrict__ ws) {
  __shared__ __align__(16) char lraw[65536];
  u16* wb = (u16*)(ws + WB_OFF);
  float* b1 = (float*)(ws + B1_OFF);
  const u16* x0b = (const u16*)(ws + X0_OFF);
  const u16* ht0b = (const u16*)(ws + HT0_OFF);
  u16* g1b = (u16*)(ws + G1_OFF);

  const int tid = threadIdx.x, gid = blockIdx.x;
  const int r = gid >> 5, c16 = gid & 31;
  const int rbase = r * 32, cbase = c16 * 16;
  const int w2 = tid >> 6, lane = tid & 63, l15 = lane & 15, kg = lane >> 4;
  const int g = w2 >> 1, m = w2 & 1;
  const float bias1l = b1[g * 512 + cbase + l15];

  #pragma unroll
  for (int p = 0; p < 8; ++p) {   // stage [x0 | ht0]
    int ch = p * 512 + tid;
    int row = ch >> 7, cc = ch & 127;
    const u16* sp = (cc < 64) ? x0b + (size_t)(rbase + row) * 512 + cc * 8
                              : ht0b + (size_t)(rbase + row) * 512 + (cc - 64) * 8;
    u32x4 v = *(const u32x4*)sp;
    *(u32x4*)&lraw[(row << 11) | ((cc << 4) ^ ((row & 7) << 4))] = v;
  }
  __syncthreads();
  f32x4 acc = {0.f, 0.f, 0.f, 0.f};
  {
    const int abase = (m * 16 + l15) << 11;
    const int axor = ((m * 16 + l15) & 7) << 4;
    const u16* W0 = wb + 2ull * 2048 * 512 + (size_t)(g * 512 + cbase + l15) * 512; // Wih1
    const u16* W1 = W0 + 2048ull * 512;                                              // Whh1
    #pragma unroll
    for (int ks = 0; ks < 16; ++ks) {
      int kk = ks * 32 + kg * 8;
      bf16x8 a = *(const bf16x8*)&lraw[abase | (((kk >> 3) << 4) ^ axor)];
      bf16x8 q = *(const bf16x8*)(W0 + kk);
      acc = __builtin_amdgcn_mfma_f32_16x16x32_bf16(a, q, acc, 0, 0, 0);
    }
    #pragma unroll
    for (int ks = 0; ks < 16; ++ks) {
      int kk = ks * 32 + kg * 8;
      bf16x8 a = *(const bf16x8*)&lraw[abase | (((64 + (kk >> 3)) << 4) ^ axor)];
      bf16x8 q = *(const bf16x8*)(W1 + kk);
      acc = __builtin_amdgcn_mfma_f32_16x16x32_bf16(a, q, acc, 0, 0, 0);
    }
  }
  #pragma unroll
  for (int q = 0; q < 4; ++q) {
    int b_ = rbase + m * 16 + kg * 4 + q;
    g1b[(size_t)g * 262144 + (size_t)b_ * 512 + cbase + l15] = f2bf(acc[q] + bias1l);
  }
}

// ================= P3: scores + layer-1 update + outputs + x0(t+1) (512 wgs x 512 thr) ====
__global__ __launch_bounds__(512, 4) void p3_k(
    char* __restrict__ ws, const float* __restrict__ xg, const float* __restrict__ Win,
    const float* __restrict__ bin, const float* __restrict__ Wout,
    float* __restrict__ out, int t) {
  __shared__ u16 gFu[2176];   // [4][32][17]
  __shared__ float sv[16];
  u16* x0b = (u16*)(ws + X0_OFF);
  u16* htb = (u16*)(ws + HT_OFF);
  const u16* g0b = (const u16*)(ws + G0_OFF);
  const u16* g1b = (const u16*)(ws + G1_OFF);
  float* ctb = (float*)(ws + CT_OFF);
  float* vspb = (float*)(ws + VSP_OFF);

  const int tid = threadIdx.x, gid = blockIdx.x;
  const int r = gid >> 5, c16 = gid & 31;
  const int rbase = r * 32, cbase = c16 * 16;
  const int w2 = tid >> 6, lane = tid & 63, l15 = lane & 15, kg = lane >> 4;
  const int g = w2 >> 1, m = w2 & 1;
  const int urow = tid >> 4, ucol = tid & 15;
  const int ub = rbase + urow, uh = cbase + ucol;

  {
    f32x4 acc = {0.f, 0.f, 0.f, 0.f};
    const u16* As = g0b + (size_t)g * 262144 + (size_t)(rbase + m * 16 + l15) * 512;
    const u16* Bs = g1b + (size_t)g * 262144 + (size_t)(cbase + l15) * 512;
    #pragma unroll
    for (int ks = 0; ks < 16; ++ks) {
      int kk = ks * 32 + kg * 8;
      bf16x8 a = *(const bf16x8*)(As + kk);
      bf16x8 q = *(const bf16x8*)(Bs + kk);
      acc = __builtin_amdgcn_mfma_f32_16x16x32_bf16(a, q, acc, 0, 0, 0);
    }
    float s1 = acc[0] + acc[1] + acc[2] + acc[3];
    float s2 = acc[0] * acc[0] + acc[1] * acc[1] + acc[2] * acc[2] + acc[3] * acc[3];
    #pragma unroll
    for (int off = 32; off > 0; off >>= 1) { s1 += __shfl_xor(s1, off); s2 += __shfl_xor(s2, off); }
    if (lane == 0) { sv[w2 * 2] = s1; sv[w2 * 2 + 1] = s2; }
    #pragma unroll
    for (int q = 0; q < 4; ++q)
      gFu[g * 544 + (m * 16 + kg * 4 + q) * 17 + l15] = f2bf(acc[q]);
  }
  __syncthreads();
  {
    float i1 = sigf(bf2f(gFu[0 * 544 + urow * 17 + ucol]));
    float f1 = sigf(bf2f(gFu[1 * 544 + urow * 17 + ucol]));
    float c1 = tanha(bf2f(gFu[2 * 544 + urow * 17 + ucol]));
    float o1 = sigf(bf2f(gFu[3 * 544 + urow * 17 + ucol]));
    size_t eo = (size_t)ub * 512 + uh;
    float ctv = ctb[eo];
    ctv = f1 * ctv + i1 * c1;
    float hv = o1 * tanha(ctv);
    ctb[eo] = ctv;
    htb[eo] = f2bf(hv);
    float op = hv * Wout[uh];
    op += __shfl_down(op, 8, 16);
    op += __shfl_down(op, 4, 16);
    op += __shfl_down(op, 2, 16);
    op += __shfl_down(op, 1, 16);
    if ((tid & 15) == 0) atomicAdd(out + (size_t)t * NB + ub, op);
    if (tid < 8) {   // per-wg variance slot
      int gg = tid >> 1, part = tid & 1;
      float val = sv[(gg * 2 + 0) * 2 + part] + sv[(gg * 2 + 1) * 2 + part];
      vspb[((size_t)gid * 8 + tid) * 368 + t] = val;
    }
    if (t + 1 < NT) {   // next step's input projection (p3 never reads x0b — R11 rule)
      const float* xr = xg + ((size_t)(t + 1) * NB + ub) * NX4;
      const float* wr = Win + (size_t)uh * NX4;
      float a = bin[uh];
      #pragma unroll
      for (int j = 0; j < 16; ++j) a += wr[j] * xr[j];
      x0b[eo] = f2bf(fmaxf(a, 0.0f));
    }
  }
}

// ================= variance / final =================
__global__ __launch_bounds__(256) void var_k(char* __restrict__ ws) {
  __shared__ float sred[8];
  float* vspb = (float*)(ws + VSP_OFF);
  float* normp = (float*)(ws + NRM_OFF);
  const int tt = blockIdx.x;
  const int tid = threadIdx.x;
  const int s = tid >> 5, jb = tid & 31;
  float v = 0.0f;
  for (int j = jb; j < 512; j += 32) v += vspb[((size_t)j * 8 + s) * 368 + tt];
  #pragma unroll
  for (int off = 16; off > 0; off >>= 1) v += __shfl_xor(v, off, 32);
  if (jb == 0) sred[s] = v;
  __syncthreads();
  if (tid == 0) {
    const float invN = 1.0f / 262144.0f;
    float var4 = 0.0f;
    #pragma unroll
    for (int gg = 0; gg < 4; ++gg) {
      float sum = sred[gg * 2 + 0];
      float sq  = sred[gg * 2 + 1];
      float mean = sum * invN;
      var4 += sq * invN - mean * mean;
    }
    normp[tt] = var4 * 0.25f;
  }
}

__global__ __launch_bounds__(512) void final_k(char* __restrict__ ws, float* __restrict__ out) {
  __shared__ float red[8];
  float* normp = (float*)(ws + NRM_OFF);
  const int tid = threadIdx.x;
  float s = (tid < NT) ? normp[tid] : 0.0f;
  #pragma unroll
  for (int off = 32; off > 0; off >>= 1) s += __shfl_xor(s, off);
  if ((tid & 63) == 0) red[tid >> 6] = s;
  __syncthreads();
  if (tid == 0) {
    float tot = 0.0f;
    #pragma unroll
    for (int j = 0; j < 8; ++j) tot += red[j];
    out[NT * NB] = tot / (float)NT;
  }
}

extern "C" void kernel_launch(void* const* d_in, const int* in_sizes, int n_in,
                              void* d_out, int out_size, void* d_ws, size_t ws_size,
                              hipStream_t stream) {
  const float* xg = (const float*)d_in[0];
  const float* Win = (const float*)d_in[1];
  const float* bin = (const float*)d_in[2];
  const float* Wih0 = (const float*)d_in[3];
  const float* bih0 = (const float*)d_in[4];
  const float* Whh0 = (const float*)d_in[5];
  const float* bhh0 = (const float*)d_in[6];
  const float* Wih1 = (const float*)d_in[7];
  const float* bih1 = (const float*)d_in[8];
  const float* Whh1 = (const float*)d_in[9];
  const float* bhh1 = (const float*)d_in[10];
  const float* Wout = (const float*)d_in[11];
  const float* bout = (const float*)d_in[12];
  float* out = (float*)d_out;
  char* ws = (char*)d_ws;

  hipLaunchKernelGGL(prep_k, dim3(256), dim3(1024), 0, stream,
                     xg, Win, bin, Wih0, bih0, Whh0, bhh0, Wih1, bih1, Whh1, bhh1,
                     bout, out, ws);
  for (int t = 0; t < NT; ++t) {
    hipLaunchKernelGGL(p1_k, dim3(512), dim3(512), 0, stream, ws);
    hipLaunchKernelGGL(p2_k, dim3(512), dim3(512), 0, stream, ws);
    hipLaunchKernelGGL(p3_k, dim3(512), dim3(512), 0, stream, ws, xg, Win, bin, Wout, out, t);
  }
  hipLaunchKernelGGL(var_k, dim3(365), dim3(256), 0, stream, ws);
  hipLaunchKernelGGL(final_k, dim3(1), dim3(512), 0, stream, ws, out);
}

// Round 14
// 20329.234 us; speedup vs baseline: 1.4866x; 1.0978x over previous
//
#include <hip/hip_runtime.h>

// ---- problem constants ----
#define NT 365
#define NB 512          // ngrid == hidden
#define NX4 16

typedef __attribute__((ext_vector_type(8))) short bf16x8;
typedef __attribute__((ext_vector_type(4))) float f32x4;
typedef __attribute__((ext_vector_type(4))) unsigned int u32x4;
typedef unsigned short u16;
typedef unsigned int u32;

// ---- workspace layout (bytes); R9 layout ----
static constexpr size_t WB_OFF  = 0;                                   // 4 x [2048][512] bf16
static constexpr size_t B0_OFF  = WB_OFF + 4ull * 2048 * 512 * 2;      // 2048 f32
static constexpr size_t B1_OFF  = B0_OFF + 2048 * 4;
static constexpr size_t X0_OFF  = B1_OFF + 2048 * 4;                   // [512][512] bf16
static constexpr size_t HT_OFF  = X0_OFF + 512 * 512 * 2;
static constexpr size_t HT0_OFF = HT_OFF + 512 * 512 * 2;
static constexpr size_t G0_OFF  = HT0_OFF + 512 * 512 * 2;             // 4 x [512][512] bf16
static constexpr size_t G1_OFF  = G0_OFF + 4ull * 512 * 512 * 2;       // 4 x [512][512] bf16
static constexpr size_t CT_OFF  = G1_OFF + 4ull * 512 * 512 * 2;       // [512][512] f32
static constexpr size_t VSP_OFF = CT_OFF + 512ull * 512 * 4;           // [256 wg][8 slot][368] f32
static constexpr size_t NRM_OFF = VSP_OFF + 256ull * 8 * 368 * 4;      // [368] f32

__device__ __forceinline__ u16 f2bf(float f) {
  u32 u = __builtin_bit_cast(u32, f);
  return (u16)((u + 0x7fffu + ((u >> 16) & 1u)) >> 16);
}
__device__ __forceinline__ float bf2f(u16 h) {
  u32 u = ((u32)h) << 16;
  return __builtin_bit_cast(float, u);
}
__device__ __forceinline__ float sigf(float x) { return 1.0f / (1.0f + __expf(-x)); }
__device__ __forceinline__ float tanha(float x) { return 1.0f - 2.0f / (__expf(2.0f * x) + 1.0f); }

// Super-tile XCD mapping: XCD x = gid%8 owns r in [4*(x>>1),+4) x c in [8*(x&1),+8).
// Cuts per-XCD staged-row and g0 replication vs c-major. Perf heuristic only.
__device__ __forceinline__ void tile_rc(int gid, int& r, int& c) {
  int x = gid & 7, k = gid >> 3;        // k: 32 cells per XCD
  r = ((x >> 1) << 2) | (k & 3);        // 4 r-groups per XCD
  c = ((x & 1) << 3) | (k >> 2);        // 8 c-groups per XCD
}

// ================= prep =================
__global__ __launch_bounds__(1024) void prep_k(
    const float* __restrict__ xg, const float* __restrict__ Win, const float* __restrict__ bin,
    const float* __restrict__ Wih0, const float* __restrict__ bih0,
    const float* __restrict__ Whh0, const float* __restrict__ bhh0,
    const float* __restrict__ Wih1, const float* __restrict__ bih1,
    const float* __restrict__ Whh1, const float* __restrict__ bhh1,
    const float* __restrict__ bout, float* __restrict__ out, char* __restrict__ ws) {
  u16* wb = (u16*)(ws + WB_OFF);
  float* b0 = (float*)(ws + B0_OFF);
  float* b1 = (float*)(ws + B1_OFF);
  u16* x0b = (u16*)(ws + X0_OFF);
  u16* htb = (u16*)(ws + HT_OFF);
  float* ctb = (float*)(ws + CT_OFF);
  const int gtid = blockIdx.x * 1024 + threadIdx.x;   // 0..262143

  const float* srcs[4] = {Wih0, Whh0, Wih1, Whh1};
  #pragma unroll
  for (int mm = 0; mm < 4; ++mm) {
    const float4* s4 = (const float4*)srcs[mm];
    float4 v = s4[gtid];
    ushort4 o;
    o.x = f2bf(v.x); o.y = f2bf(v.y); o.z = f2bf(v.z); o.w = f2bf(v.w);
    ((ushort4*)(wb + (size_t)mm * 2048 * 512))[gtid] = o;
  }
  if (gtid < 2048) { b0[gtid] = bih0[gtid] + bhh0[gtid]; b1[gtid] = bih1[gtid] + bhh1[gtid]; }
  if (gtid < 131072) ((u32*)htb)[gtid] = 0u;
  ctb[gtid] = 0.0f;
  { // x0 for t=0
    int b = gtid >> 9, h = gtid & 511;
    const float* xr = xg + (size_t)b * NX4;
    const float* wr = Win + (size_t)h * NX4;
    float a = bin[h];
    #pragma unroll
    for (int j = 0; j < 16; ++j) a += wr[j] * xr[j];
    x0b[gtid] = f2bf(fmaxf(a, 0.0f));
  }
  { // out = bias
    float bo = bout[0];
    for (int j = gtid; j < NT * NB; j += 262144) out[j] = bo;
  }
}

// ================= P1: layer-0 gates + cell update =================
__global__ __launch_bounds__(1024) void p1_k(char* __restrict__ ws) {
  __shared__ __align__(16) char lraw[65536];
  u16* gFu = (u16*)lraw;
  u16* wb = (u16*)(ws + WB_OFF);
  float* b0 = (float*)(ws + B0_OFF);
  const u16* x0b = (const u16*)(ws + X0_OFF);
  const u16* htb = (const u16*)(ws + HT_OFF);
  u16* ht0b = (u16*)(ws + HT0_OFF);
  u16* g0b = (u16*)(ws + G0_OFF);
  float* ctb = (float*)(ws + CT_OFF);

  const int tid = threadIdx.x, gid = blockIdx.x;
  int r, c; tile_rc(gid, r, c);
  const int rbase = r * 32, cbase = c * 32;
  const int w = tid >> 6, lane = tid & 63, l15 = lane & 15, kg = lane >> 4;
  const int g = w >> 2, m = (w >> 1) & 1, n = w & 1;
  const int urow = tid >> 5, ucol = tid & 31;
  const int ub = rbase + urow, uh = cbase + ucol;
  const int arow = m * 16 + l15, abase = arow << 11, axor = (arow & 7) << 4;
  const u16* Wl0 = wb + (size_t)(g * 512 + cbase + n * 16 + l15) * 512;
  const float bias0l = b0[g * 512 + cbase + n * 16 + l15];

  #pragma unroll
  for (int p = 0; p < 4; ++p) {   // stage [x0 | ht] rows rbase..+32 (64KB, swizzled)
    int ch = p * 1024 + tid;
    int row = ch >> 7, cc = ch & 127;
    const u16* sp = (cc < 64) ? x0b + (size_t)(rbase + row) * 512 + cc * 8
                              : htb + (size_t)(rbase + row) * 512 + (cc - 64) * 8;
    u32x4 v = *(const u32x4*)sp;
    *(u32x4*)&lraw[(row << 11) | ((cc << 4) ^ ((row & 7) << 4))] = v;
  }
  __syncthreads();
  f32x4 acc = {0.f, 0.f, 0.f, 0.f};
  {
    const u16* W0 = Wl0;                       // Wih0 row
    const u16* W1 = Wl0 + 2048ull * 512;       // Whh0 row
    #pragma unroll
    for (int ks = 0; ks < 16; ++ks) {
      int kk = ks * 32 + kg * 8;
      bf16x8 a = *(const bf16x8*)&lraw[abase | (((kk >> 3) << 4) ^ axor)];
      bf16x8 q = *(const bf16x8*)(W0 + kk);
      acc = __builtin_amdgcn_mfma_f32_16x16x32_bf16(a, q, acc, 0, 0, 0);
    }
    #pragma unroll
    for (int ks = 0; ks < 16; ++ks) {
      int kk = ks * 32 + kg * 8;
      bf16x8 a = *(const bf16x8*)&lraw[abase | (((64 + (kk >> 3)) << 4) ^ axor)];
      bf16x8 q = *(const bf16x8*)(W1 + kk);
      acc = __builtin_amdgcn_mfma_f32_16x16x32_bf16(a, q, acc, 0, 0, 0);
    }
  }
  __syncthreads();  // staging dead; reuse LDS as gFu
  #pragma unroll
  for (int q = 0; q < 4; ++q) {
    float v = acc[q] + bias0l;
    float a = (g == 2) ? tanha(v) : sigf(v);
    gFu[g * 1280 + (m * 16 + kg * 4 + q) * 40 + n * 16 + l15] = f2bf(a);
  }
  __syncthreads();
  {
    u16 gi = gFu[0 * 1280 + urow * 40 + ucol];
    u16 gf = gFu[1 * 1280 + urow * 40 + ucol];
    u16 gc = gFu[2 * 1280 + urow * 40 + ucol];
    u16 go = gFu[3 * 1280 + urow * 40 + ucol];
    float i0 = bf2f(gi), f0 = bf2f(gf), c0 = bf2f(gc), o0 = bf2f(go);
    size_t eo = (size_t)ub * 512 + uh;
    float ctv = ctb[eo];
    ctv = f0 * ctv + i0 * c0;
    float h0v = o0 * tanha(ctv);
    ctb[eo] = ctv;
    ht0b[eo] = f2bf(h0v);
    g0b[0 * 262144 + eo] = gi;
    g0b[1 * 262144 + eo] = gf;
    g0b[2 * 262144 + eo] = gc;
    g0b[3 * 262144 + eo] = go;
  }
}

// ================= P2: layer-1 raw gates =================
__global__ __launch_bounds__(1024) void p2_k(char* __restrict__ ws) {
  __shared__ __align__(16) char lraw[65536];
  u16* wb = (u16*)(ws + WB_OFF);
  float* b1 = (float*)(ws + B1_OFF);
  const u16* x0b = (const u16*)(ws + X0_OFF);
  const u16* ht0b = (const u16*)(ws + HT0_OFF);
  u16* g1b = (u16*)(ws + G1_OFF);

  const int tid = threadIdx.x, gid = blockIdx.x;
  int r, c; tile_rc(gid, r, c);
  const int rbase = r * 32, cbase = c * 32;
  const int w = tid >> 6, lane = tid & 63, l15 = lane & 15, kg = lane >> 4;
  const int g = w >> 2, m = (w >> 1) & 1, n = w & 1;
  const int arow = m * 16 + l15, abase = arow << 11, axor = (arow & 7) << 4;
  const u16* Wl0 = wb + (size_t)(g * 512 + cbase + n * 16 + l15) * 512;
  const float bias1l = b1[g * 512 + cbase + n * 16 + l15];

  #pragma unroll
  for (int p = 0; p < 4; ++p) {   // stage [x0 | ht0]
    int ch = p * 1024 + tid;
    int row = ch >> 7, cc = ch & 127;
    const u16* sp = (cc < 64) ? x0b + (size_t)(rbase + row) * 512 + cc * 8
                              : ht0b + (size_t)(rbase + row) * 512 + (cc - 64) * 8;
    u32x4 v = *(const u32x4*)sp;
    *(u32x4*)&lraw[(row << 11) | ((cc << 4) ^ ((row & 7) << 4))] = v;
  }
  __syncthreads();
  f32x4 acc = {0.f, 0.f, 0.f, 0.f};
  {
    const u16* W0 = Wl0 + 2ull * 2048 * 512;   // Wih1
    const u16* W1 = Wl0 + 3ull * 2048 * 512;   // Whh1
    #pragma unroll
    for (int ks = 0; ks < 16; ++ks) {
      int kk = ks * 32 + kg * 8;
      bf16x8 a = *(const bf16x8*)&lraw[abase | (((kk >> 3) << 4) ^ axor)];
      bf16x8 q = *(const bf16x8*)(W0 + kk);
      acc = __builtin_amdgcn_mfma_f32_16x16x32_bf16(a, q, acc, 0, 0, 0);
    }
    #pragma unroll
    for (int ks = 0; ks < 16; ++ks) {
      int kk = ks * 32 + kg * 8;
      bf16x8 a = *(const bf16x8*)&lraw[abase | (((64 + (kk >> 3)) << 4) ^ axor)];
      bf16x8 q = *(const bf16x8*)(W1 + kk);
      acc = __builtin_amdgcn_mfma_f32_16x16x32_bf16(a, q, acc, 0, 0, 0);
    }
  }
  #pragma unroll
  for (int q = 0; q < 4; ++q) {
    int b_ = rbase + m * 16 + kg * 4 + q;
    g1b[(size_t)g * 262144 + (size_t)b_ * 512 + cbase + n * 16 + l15] = f2bf(acc[q] + bias1l);
  }
}

// ================= P3: [B,B] score matmuls + layer-1 update + outputs + x0(t+1) =================
__global__ __launch_bounds__(1024) void p3_k(
    char* __restrict__ ws, const float* __restrict__ xg, const float* __restrict__ Win,
    const float* __restrict__ bin, const float* __restrict__ Wout,
    float* __restrict__ out, int t) {
  __shared__ u16 gFu[5120];
  __shared__ float sv[32];
  u16* x0b = (u16*)(ws + X0_OFF);
  u16* htb = (u16*)(ws + HT_OFF);
  const u16* g0b = (const u16*)(ws + G0_OFF);
  const u16* g1b = (const u16*)(ws + G1_OFF);
  float* ctb = (float*)(ws + CT_OFF);
  float* vspb = (float*)(ws + VSP_OFF);

  const int tid = threadIdx.x, gid = blockIdx.x;
  int r, c; tile_rc(gid, r, c);
  const int rbase = r * 32, cbase = c * 32;
  const int w = tid >> 6, lane = tid & 63, l15 = lane & 15, kg = lane >> 4;
  const int g = w >> 2, m = (w >> 1) & 1, n = w & 1;
  const int urow = tid >> 5, ucol = tid & 31;
  const int ub = rbase + urow, uh = cbase + ucol;

  {
    f32x4 acc = {0.f, 0.f, 0.f, 0.f};
    const u16* As = g0b + (size_t)g * 262144 + (size_t)(rbase + m * 16 + l15) * 512;
    const u16* Bs = g1b + (size_t)g * 262144 + (size_t)(cbase + n * 16 + l15) * 512;
    #pragma unroll
    for (int ks = 0; ks < 16; ++ks) {
      int kk = ks * 32 + kg * 8;
      bf16x8 a = *(const bf16x8*)(As + kk);
      bf16x8 q = *(const bf16x8*)(Bs + kk);
      acc = __builtin_amdgcn_mfma_f32_16x16x32_bf16(a, q, acc, 0, 0, 0);
    }
    float s1 = acc[0] + acc[1] + acc[2] + acc[3];
    float s2 = acc[0] * acc[0] + acc[1] * acc[1] + acc[2] * acc[2] + acc[3] * acc[3];
    #pragma unroll
    for (int off = 32; off > 0; off >>= 1) { s1 += __shfl_xor(s1, off); s2 += __shfl_xor(s2, off); }
    if (lane == 0) { sv[w * 2] = s1; sv[w * 2 + 1] = s2; }
    #pragma unroll
    for (int q = 0; q < 4; ++q)
      gFu[g * 1280 + (m * 16 + kg * 4 + q) * 40 + n * 16 + l15] = f2bf(acc[q]);
  }
  __syncthreads();
  {
    float i1 = sigf(bf2f(gFu[0 * 1280 + urow * 40 + ucol]));
    float f1 = sigf(bf2f(gFu[1 * 1280 + urow * 40 + ucol]));
    float c1 = tanha(bf2f(gFu[2 * 1280 + urow * 40 + ucol]));
    float o1 = sigf(bf2f(gFu[3 * 1280 + urow * 40 + ucol]));
    size_t eo = (size_t)ub * 512 + uh;
    float ctv = ctb[eo];
    ctv = f1 * ctv + i1 * c1;
    float hv = o1 * tanha(ctv);
    ctb[eo] = ctv;
    htb[eo] = f2bf(hv);
    float op = hv * Wout[uh];
    op += __shfl_down(op, 16, 32);
    op += __shfl_down(op, 8, 32);
    op += __shfl_down(op, 4, 32);
    op += __shfl_down(op, 2, 32);
    op += __shfl_down(op, 1, 32);
    if ((tid & 31) == 0) atomicAdd(out + (size_t)t * NB + ub, op);
    if (tid < 8) {   // per-wg variance slot
      int gg = tid >> 1, part = tid & 1;
      float val = sv[(gg * 4 + 0) * 2 + part] + sv[(gg * 4 + 1) * 2 + part] +
                  sv[(gg * 4 + 2) * 2 + part] + sv[(gg * 4 + 3) * 2 + part];
      vspb[((size_t)gid * 8 + tid) * 368 + t] = val;
    }
    if (t + 1 < NT) {   // next step's input projection (p3 never reads x0b — R11 rule)
      const float* xr = xg + ((size_t)(t + 1) * NB + ub) * NX4;
      const float* wr = Win + (size_t)uh * NX4;
      float a = bin[uh];
      #pragma unroll
      for (int j = 0; j < 16; ++j) a += wr[j] * xr[j];
      x0b[eo] = f2bf(fmaxf(a, 0.0f));
    }
  }
}

// ================= variance / final =================
__global__ __launch_bounds__(256) void var_k(char* __restrict__ ws) {
  __shared__ float sred[8];
  float* vspb = (float*)(ws + VSP_OFF);
  float* normp = (float*)(ws + NRM_OFF);
  const int tt = blockIdx.x;
  const int tid = threadIdx.x;
  const int s = tid >> 5, jb = tid & 31;
  float v = 0.0f;
  for (int j = jb; j < 256; j += 32) v += vspb[((size_t)j * 8 + s) * 368 + tt];
  #pragma unroll
  for (int off = 16; off > 0; off >>= 1) v += __shfl_xor(v, off, 32);
  if (jb == 0) sred[s] = v;
  __syncthreads();
  if (tid == 0) {
    const float invN = 1.0f / 262144.0f;
    float var4 = 0.0f;
    #pragma unroll
    for (int gg = 0; gg < 4; ++gg) {
      float sum = sred[gg * 2 + 0];
      float sq  = sred[gg * 2 + 1];
      float mean = sum * invN;
      var4 += sq * invN - mean * mean;
    }
    normp[tt] = var4 * 0.25f;
  }
}

__global__ __launch_bounds__(512) void final_k(char* __restrict__ ws, float* __restrict__ out) {
  __shared__ float red[8];
  float* normp = (float*)(ws + NRM_OFF);
  const int tid = threadIdx.x;
  float s = (tid < NT) ? normp[tid] : 0.0f;
  #pragma unroll
  for (int off = 32; off > 0; off >>= 1) s += __shfl_xor(s, off);
  if ((tid & 63) == 0) red[tid >> 6] = s;
  __syncthreads();
  if (tid == 0) {
    float tot = 0.0f;
    #pragma unroll
    for (int j = 0; j < 8; ++j) tot += red[j];
    out[NT * NB] = tot / (float)NT;
  }
}

extern "C" void kernel_launch(void* const* d_in, const int* in_sizes, int n_in,
                              void* d_out, int out_size, void* d_ws, size_t ws_size,
                              hipStream_t stream) {
  const float* xg = (const float*)d_in[0];
  const float* Win = (const float*)d_in[1];
  const float* bin = (const float*)d_in[2];
  const float* Wih0 = (const float*)d_in[3];
  const float* bih0 = (const float*)d_in[4];
  const float* Whh0 = (const float*)d_in[5];
  const float* bhh0 = (const float*)d_in[6];
  const float* Wih1 = (const float*)d_in[7];
  const float* bih1 = (const float*)d_in[8];
  const float* Whh1 = (const float*)d_in[9];
  const float* bhh1 = (const float*)d_in[10];
  const float* Wout = (const float*)d_in[11];
  const float* bout = (const float*)d_in[12];
  float* out = (float*)d_out;
  char* ws = (char*)d_ws;

  hipLaunchKernelGGL(prep_k, dim3(256), dim3(1024), 0, stream,
                     xg, Win, bin, Wih0, bih0, Whh0, bhh0, Wih1, bih1, Whh1, bhh1,
                     bout, out, ws);
  for (int t = 0; t < NT; ++t) {
    hipLaunchKernelGGL(p1_k, dim3(256), dim3(1024), 0, stream, ws);
    hipLaunchKernelGGL(p2_k, dim3(256), dim3(1024), 0, stream, ws);
    hipLaunchKernelGGL(p3_k, dim3(256), dim3(1024), 0, stream, ws, xg, Win, bin, Wout, out, t);
  }
  hipLaunchKernelGGL(var_k, dim3(365), dim3(256), 0, stream, ws);
  hipLaunchKernelGGL(final_k, dim3(1), dim3(512), 0, stream, ws, out);
}